// Round 12
// baseline (156.215 us; speedup 1.0000x reference)
//
#include <hip/hip_runtime.h>

// LQActiv forward: 2-bit quantization + least-squares basis refit.
// Output layout: [N floats wq][2 floats new_basis].
//
// Round 12: FULL-RANGE readable A/B (round 10's quarter-split was clipped
// by the harness's 59us fill dispatches; >=60us dispatches do show).
// Empirical law so far: store-bearing kernels pay ~6us per VALU-inst/elem
// (copy=32, quant6=70, fused13=135) while read-only pay ~0.8 (reduce=15,
// stats7=20). Two full-range quant variants, V2 overwrites V1 (output
// stays correct):
//   V1: CACHED loads + NT store, 6-inst chain  -> load-policy A/B vs
//       round-8's NT/NT 6-inst (74.7us).
//   V2: CACHED loads + NT store, 12-inst chain quant(quant(w)) — levels
//       are fixed points, output provably identical -> VALU-dose A/B.
// Readout: per-dispatch rows (if >=60us) + headline differencing.

#define NBLOCKS 2048
#define NTHREADS 256

typedef float fvec4 __attribute__((ext_vector_type(4)));

// ---- K1: stats only (reduce shape) — unchanged ----
__global__ __launch_bounds__(NTHREADS) void lq_stats(
    const float* __restrict__ x, const float* __restrict__ basis,
    float* __restrict__ partials, int n4) {
  const float v0 = basis[0], v1 = basis[1];
  float lev[4] = {-v0 - v1, -v0 + v1, v0 - v1, v0 + v1};
#define CSWAP(i, j)                                          \
  if (lev[i] > lev[j]) { float t = lev[i]; lev[i] = lev[j]; lev[j] = t; }
  CSWAP(0, 1) CSWAP(2, 3) CSWAP(0, 2) CSWAP(1, 3) CSWAP(1, 2)
#undef CSWAP
  const float T0 = 0.5f * (lev[0] + lev[1]);
  const float T1 = 0.5f * (lev[1] + lev[2]);
  const float T2 = 0.5f * (lev[2] + lev[3]);

  int c0 = 0, c1 = 0, c2 = 0;
  float sw = 0.f, sw0 = 0.f, sw1 = 0.f, sw2 = 0.f;

  auto acc = [&](float w) {
    const bool t0 = w > T0;
    const bool t1 = w > T1;
    const bool t2 = w > T2;
    c0 += t0;
    c1 += t1;
    c2 += t2;
    sw += w;
    sw0 += t0 ? w : 0.f;
    sw1 += t1 ? w : 0.f;
    sw2 += t2 ? w : 0.f;
  };

  const fvec4* __restrict__ x4 = (const fvec4*)x;
  const int tid = blockIdx.x * blockDim.x + threadIdx.x;
  const int stride = gridDim.x * blockDim.x;
  for (int i = tid; i < n4; i += stride) {
    fvec4 w = __builtin_nontemporal_load(&x4[i]);
    acc(w.x);
    acc(w.y);
    acc(w.z);
    acc(w.w);
  }

  float f0 = (float)c0, f1 = (float)c1, f2 = (float)c2;
  for (int off = 32; off; off >>= 1) {
    f0 += __shfl_down(f0, off);
    f1 += __shfl_down(f1, off);
    f2 += __shfl_down(f2, off);
    sw += __shfl_down(sw, off);
    sw0 += __shfl_down(sw0, off);
    sw1 += __shfl_down(sw1, off);
    sw2 += __shfl_down(sw2, off);
  }
  __shared__ float red[7][NTHREADS / 64];
  const int lane = threadIdx.x & 63;
  const int wid = threadIdx.x >> 6;
  if (lane == 0) {
    red[0][wid] = f0;
    red[1][wid] = f1;
    red[2][wid] = f2;
    red[3][wid] = sw;
    red[4][wid] = sw0;
    red[5][wid] = sw1;
    red[6][wid] = sw2;
  }
  __syncthreads();
  if (threadIdx.x < 7) {
    float r = 0.f;
#pragma unroll
    for (int w = 0; w < NTHREADS / 64; ++w) r += red[threadIdx.x][w];
    partials[7 * blockIdx.x + threadIdx.x] = r;
  }
}

// ---- shared level derivation ----
__device__ __forceinline__ void sorted_levels(const float* basis, float& Q0,
                                              float& Q1, float& Q2, float& Q3) {
  const float v0 = basis[0], v1 = basis[1];
  float lev[4] = {-v0 - v1, -v0 + v1, v0 - v1, v0 + v1};
#define CSWAP(i, j)                                          \
  if (lev[i] > lev[j]) { float t = lev[i]; lev[i] = lev[j]; lev[j] = t; }
  CSWAP(0, 1) CSWAP(2, 3) CSWAP(0, 2) CSWAP(1, 3) CSWAP(1, 2)
#undef CSWAP
  Q0 = lev[0];
  Q1 = lev[1];
  Q2 = lev[2];
  Q3 = lev[3];
}

// ---- V1: CACHED load / NT store, 6-inst chain (load-policy A/B) ----
__global__ __launch_bounds__(NTHREADS) void lq_qV1_c6(
    const float* __restrict__ x, const float* __restrict__ basis,
    float* __restrict__ out, int n, int n4) {
  float Q0, Q1, Q2, Q3;
  sorted_levels(basis, Q0, Q1, Q2, Q3);
  const float T0 = 0.5f * (Q0 + Q1);
  const float T1 = 0.5f * (Q1 + Q2);
  const float T2 = 0.5f * (Q2 + Q3);
  auto quant = [&](float w) -> float {
    float q = (w > T0) ? Q1 : Q0;
    q = (w > T1) ? Q2 : q;
    q = (w > T2) ? Q3 : q;
    return q;
  };
  const fvec4* __restrict__ x4 = (const fvec4*)x;
  fvec4* __restrict__ o4 = (fvec4*)out;
  const int tid = blockIdx.x * blockDim.x + threadIdx.x;
  const int stride = gridDim.x * blockDim.x;
  for (int i = tid; i < n4; i += stride) {
    fvec4 w = x4[i];  // cached load
    fvec4 q;
    q.x = quant(w.x);
    q.y = quant(w.y);
    q.z = quant(w.z);
    q.w = quant(w.w);
    __builtin_nontemporal_store(q, &o4[i]);
  }
  for (int k = n4 * 4 + tid; k < n; k += stride) {
    out[k] = quant(x[k]);
  }
}

// ---- V2: CACHED load / NT store, 12-inst double-applied chain ----
// quant(quant(w)) == quant(w): every level is a fixed point of the
// quantizer (each Qk lies strictly inside its own bucket). Pure VALU-dose
// probe with provably identical output.
__global__ __launch_bounds__(NTHREADS) void lq_qV2_c12(
    const float* __restrict__ x, const float* __restrict__ basis,
    float* __restrict__ out, int n, int n4) {
  float Q0, Q1, Q2, Q3;
  sorted_levels(basis, Q0, Q1, Q2, Q3);
  const float T0 = 0.5f * (Q0 + Q1);
  const float T1 = 0.5f * (Q1 + Q2);
  const float T2 = 0.5f * (Q2 + Q3);
  auto quant = [&](float w) -> float {
    float q = (w > T0) ? Q1 : Q0;
    q = (w > T1) ? Q2 : q;
    q = (w > T2) ? Q3 : q;
    return q;
  };
  auto quant2 = [&](float w) -> float { return quant(quant(w)); };
  const fvec4* __restrict__ x4 = (const fvec4*)x;
  fvec4* __restrict__ o4 = (fvec4*)out;
  const int tid = blockIdx.x * blockDim.x + threadIdx.x;
  const int stride = gridDim.x * blockDim.x;
  for (int i = tid; i < n4; i += stride) {
    fvec4 w = x4[i];  // cached load
    fvec4 q;
    q.x = quant2(w.x);
    q.y = quant2(w.y);
    q.z = quant2(w.z);
    q.w = quant2(w.w);
    __builtin_nontemporal_store(q, &o4[i]);
  }
  for (int k = n4 * 4 + tid; k < n; k += stride) {
    out[k] = quant2(x[k]);
  }
}

// ---- K3: final reduce + 2x2 solve — unchanged ----
__global__ __launch_bounds__(NTHREADS) void lq_final(
    const float* __restrict__ partials, const float* __restrict__ basis,
    float* __restrict__ out_basis, int n, int nparts) {
  double C0 = 0, C1 = 0, C2 = 0, SW = 0, SW0 = 0, SW1 = 0, SW2 = 0;
  for (int i = threadIdx.x; i < nparts; i += blockDim.x) {
    C0 += (double)partials[7 * i + 0];
    C1 += (double)partials[7 * i + 1];
    C2 += (double)partials[7 * i + 2];
    SW += (double)partials[7 * i + 3];
    SW0 += (double)partials[7 * i + 4];
    SW1 += (double)partials[7 * i + 5];
    SW2 += (double)partials[7 * i + 6];
  }
  for (int off = 32; off; off >>= 1) {
    C0 += __shfl_down(C0, off);
    C1 += __shfl_down(C1, off);
    C2 += __shfl_down(C2, off);
    SW += __shfl_down(SW, off);
    SW0 += __shfl_down(SW0, off);
    SW1 += __shfl_down(SW1, off);
    SW2 += __shfl_down(SW2, off);
  }
  __shared__ double red[7][NTHREADS / 64];
  const int lane = threadIdx.x & 63;
  const int wid = threadIdx.x >> 6;
  if (lane == 0) {
    red[0][wid] = C0;
    red[1][wid] = C1;
    red[2][wid] = C2;
    red[3][wid] = SW;
    red[4][wid] = SW0;
    red[5][wid] = SW1;
    red[6][wid] = SW2;
  }
  __syncthreads();
  if (threadIdx.x == 0) {
    double c0 = 0, c1 = 0, c2 = 0, s = 0, s0 = 0, s1 = 0, s2 = 0;
#pragma unroll
    for (int w = 0; w < NTHREADS / 64; ++w) {
      c0 += red[0][w];
      c1 += red[1][w];
      c2 += red[2][w];
      s += red[3][w];
      s0 += red[4][w];
      s1 += red[5][w];
      s2 += red[6][w];
    }
    const float v0 = basis[0], v1 = basis[1];
    float lev[4] = {-v0 - v1, -v0 + v1, v0 - v1, v0 + v1};
    float e0[4] = {-1.f, -1.f, 1.f, 1.f};
    float e1[4] = {-1.f, 1.f, -1.f, 1.f};
#define CSWAP(i, j)                                                   \
    if (lev[i] > lev[j]) {                                            \
      float t = lev[i]; lev[i] = lev[j]; lev[j] = t;                  \
      t = e0[i]; e0[i] = e0[j]; e0[j] = t;                            \
      t = e1[i]; e1[i] = e1[j]; e1[j] = t;                            \
    }
    CSWAP(0, 1) CSWAP(2, 3) CSWAP(0, 2) CSWAP(1, 3) CSWAP(1, 2)
#undef CSWAP
    const double A0 = e0[0], A1 = e0[1], A2 = e0[2], A3 = e0[3];
    const double B0 = e1[0], B1 = e1[1], B2 = e1[2], B3 = e1[3];
    const double N = (double)n;
    // telescoped sums over the monotone one-hot
    const double Sb0 = A0 * s + (A1 - A0) * s0 + (A2 - A1) * s1 + (A3 - A2) * s2;
    const double Sb1 = B0 * s + (B1 - B0) * s0 + (B2 - B1) * s1 + (B3 - B2) * s2;
    const double P0 = A0 * B0, P1 = A1 * B1, P2 = A2 * B2, P3 = A3 * B3;
    const double S01 = P0 * N + (P1 - P0) * c0 + (P2 - P1) * c1 + (P3 - P2) * c2;
    const double det = N * N - S01 * S01;
    const double nv0 = (N * Sb0 - S01 * Sb1) / det;
    const double nv1 = (N * Sb1 - S01 * Sb0) / det;
    out_basis[0] = (float)(0.9 * (double)v0 + 0.1 * nv0);
    out_basis[1] = (float)(0.9 * (double)v1 + 0.1 * nv1);
  }
}

extern "C" void kernel_launch(void* const* d_in, const int* in_sizes, int n_in,
                              void* d_out, int out_size, void* d_ws, size_t ws_size,
                              hipStream_t stream) {
  const float* x = (const float*)d_in[0];
  const float* basis = (const float*)d_in[1];
  float* out = (float*)d_out;
  const int n = in_sizes[0];
  float* partials = (float*)d_ws;  // nblocks * 7 floats

  int nblocks = NBLOCKS;
  const int maxb = (int)(ws_size / (7 * sizeof(float)));
  if (nblocks > maxb) nblocks = maxb;
  if (nblocks < 1) nblocks = 1;

  const int n4 = n / 4;
  lq_stats<<<nblocks, NTHREADS, 0, stream>>>(x, basis, partials, n4);
  // V1 then V2 (V2 overwrites -> final output from V2, provably identical)
  lq_qV1_c6<<<NBLOCKS, NTHREADS, 0, stream>>>(x, basis, out, n, n4);
  lq_qV2_c12<<<NBLOCKS, NTHREADS, 0, stream>>>(x, basis, out, n, n4);
  lq_final<<<1, NTHREADS, 0, stream>>>(partials, basis, out + n, n, nblocks);
}

// Round 13
// 80.415 us; speedup vs baseline: 1.9426x; 1.9426x over previous
//
#include <hip/hip_runtime.h>

// LQActiv forward: 2-bit quantization + least-squares basis refit.
// Output layout: [N floats wq][2 floats new_basis].
//
// Round 13: exploit the round-12 discovery. V2 (identical loads/stores,
// LONGER chain) ran ~48us vs V1's 86.2 — the only difference is V2 ran
// right after a full CACHED read of x. Mechanism: cached reads re-populate
// L3 with x (out's store stream partially evicts it each replay); the next
// pass reads x at L3 rates. So: stats becomes the warmer (plain cached
// loads instead of NT), and the single quant pass (cached load + NT store,
// 6-inst chain) runs in the warm slot.
//   K1 lq_stats: reduce-shaped, CACHED reads (warms L3), 7 partials/block.
//   K2 lq_quant: cached load + NT store, 6-inst select, 1-deep grid-stride.
//   K3 lq_final: f64 reduce + telescoped encoding algebra + 2x2 solve.

#define NBLOCKS 2048
#define NTHREADS 256

typedef float fvec4 __attribute__((ext_vector_type(4)));

// ---- K1: stats + L3 warmer (CACHED loads) ----
__global__ __launch_bounds__(NTHREADS) void lq_stats(
    const float* __restrict__ x, const float* __restrict__ basis,
    float* __restrict__ partials, int n4) {
  const float v0 = basis[0], v1 = basis[1];
  float lev[4] = {-v0 - v1, -v0 + v1, v0 - v1, v0 + v1};
#define CSWAP(i, j)                                          \
  if (lev[i] > lev[j]) { float t = lev[i]; lev[i] = lev[j]; lev[j] = t; }
  CSWAP(0, 1) CSWAP(2, 3) CSWAP(0, 2) CSWAP(1, 3) CSWAP(1, 2)
#undef CSWAP
  const float T0 = 0.5f * (lev[0] + lev[1]);
  const float T1 = 0.5f * (lev[1] + lev[2]);
  const float T2 = 0.5f * (lev[2] + lev[3]);

  int c0 = 0, c1 = 0, c2 = 0;
  float sw = 0.f, sw0 = 0.f, sw1 = 0.f, sw2 = 0.f;

  auto acc = [&](float w) {
    const bool t0 = w > T0;
    const bool t1 = w > T1;
    const bool t2 = w > T2;
    c0 += t0;
    c1 += t1;
    c2 += t2;
    sw += w;
    sw0 += t0 ? w : 0.f;
    sw1 += t1 ? w : 0.f;
    sw2 += t2 ? w : 0.f;
  };

  const fvec4* __restrict__ x4 = (const fvec4*)x;
  const int tid = blockIdx.x * blockDim.x + threadIdx.x;
  const int stride = gridDim.x * blockDim.x;
  for (int i = tid; i < n4; i += stride) {
    fvec4 w = x4[i];  // CACHED: allocates x into L2/L3 -> warms next pass
    acc(w.x);
    acc(w.y);
    acc(w.z);
    acc(w.w);
  }

  float f0 = (float)c0, f1 = (float)c1, f2 = (float)c2;
  for (int off = 32; off; off >>= 1) {
    f0 += __shfl_down(f0, off);
    f1 += __shfl_down(f1, off);
    f2 += __shfl_down(f2, off);
    sw += __shfl_down(sw, off);
    sw0 += __shfl_down(sw0, off);
    sw1 += __shfl_down(sw1, off);
    sw2 += __shfl_down(sw2, off);
  }
  __shared__ float red[7][NTHREADS / 64];
  const int lane = threadIdx.x & 63;
  const int wid = threadIdx.x >> 6;
  if (lane == 0) {
    red[0][wid] = f0;
    red[1][wid] = f1;
    red[2][wid] = f2;
    red[3][wid] = sw;
    red[4][wid] = sw0;
    red[5][wid] = sw1;
    red[6][wid] = sw2;
  }
  __syncthreads();
  if (threadIdx.x < 7) {
    float r = 0.f;
#pragma unroll
    for (int w = 0; w < NTHREADS / 64; ++w) r += red[threadIdx.x][w];
    partials[7 * blockIdx.x + threadIdx.x] = r;
  }
}

// ---- K2: quantize in the L3-warm slot (cached load / NT store) ----
__global__ __launch_bounds__(NTHREADS) void lq_quant(
    const float* __restrict__ x, const float* __restrict__ basis,
    float* __restrict__ out, int n, int n4) {
  const float v0 = basis[0], v1 = basis[1];
  float lev[4] = {-v0 - v1, -v0 + v1, v0 - v1, v0 + v1};
#define CSWAP(i, j)                                          \
  if (lev[i] > lev[j]) { float t = lev[i]; lev[i] = lev[j]; lev[j] = t; }
  CSWAP(0, 1) CSWAP(2, 3) CSWAP(0, 2) CSWAP(1, 3) CSWAP(1, 2)
#undef CSWAP
  const float Q0 = lev[0], Q1 = lev[1], Q2 = lev[2], Q3 = lev[3];
  const float T0 = 0.5f * (Q0 + Q1);
  const float T1 = 0.5f * (Q1 + Q2);
  const float T2 = 0.5f * (Q2 + Q3);

  auto quant = [&](float w) -> float {
    float q = (w > T0) ? Q1 : Q0;  // thresholds monotone:
    q = (w > T1) ? Q2 : q;         // q = Qlevels[(w>T0)+(w>T1)+(w>T2)]
    q = (w > T2) ? Q3 : q;
    return q;
  };

  const fvec4* __restrict__ x4 = (const fvec4*)x;
  fvec4* __restrict__ o4 = (fvec4*)out;
  const int tid = blockIdx.x * blockDim.x + threadIdx.x;
  const int stride = gridDim.x * blockDim.x;
  for (int i = tid; i < n4; i += stride) {
    fvec4 w = x4[i];  // cached load (V2's proven-fast config in warm slot)
    fvec4 q;
    q.x = quant(w.x);
    q.y = quant(w.y);
    q.z = quant(w.z);
    q.w = quant(w.w);
    __builtin_nontemporal_store(q, &o4[i]);
  }
  for (int k = n4 * 4 + tid; k < n; k += stride) {
    out[k] = quant(x[k]);
  }
}

// ---- K3: final reduce + 2x2 solve — unchanged ----
__global__ __launch_bounds__(NTHREADS) void lq_final(
    const float* __restrict__ partials, const float* __restrict__ basis,
    float* __restrict__ out_basis, int n, int nparts) {
  double C0 = 0, C1 = 0, C2 = 0, SW = 0, SW0 = 0, SW1 = 0, SW2 = 0;
  for (int i = threadIdx.x; i < nparts; i += blockDim.x) {
    C0 += (double)partials[7 * i + 0];
    C1 += (double)partials[7 * i + 1];
    C2 += (double)partials[7 * i + 2];
    SW += (double)partials[7 * i + 3];
    SW0 += (double)partials[7 * i + 4];
    SW1 += (double)partials[7 * i + 5];
    SW2 += (double)partials[7 * i + 6];
  }
  for (int off = 32; off; off >>= 1) {
    C0 += __shfl_down(C0, off);
    C1 += __shfl_down(C1, off);
    C2 += __shfl_down(C2, off);
    SW += __shfl_down(SW, off);
    SW0 += __shfl_down(SW0, off);
    SW1 += __shfl_down(SW1, off);
    SW2 += __shfl_down(SW2, off);
  }
  __shared__ double red[7][NTHREADS / 64];
  const int lane = threadIdx.x & 63;
  const int wid = threadIdx.x >> 6;
  if (lane == 0) {
    red[0][wid] = C0;
    red[1][wid] = C1;
    red[2][wid] = C2;
    red[3][wid] = SW;
    red[4][wid] = SW0;
    red[5][wid] = SW1;
    red[6][wid] = SW2;
  }
  __syncthreads();
  if (threadIdx.x == 0) {
    double c0 = 0, c1 = 0, c2 = 0, s = 0, s0 = 0, s1 = 0, s2 = 0;
#pragma unroll
    for (int w = 0; w < NTHREADS / 64; ++w) {
      c0 += red[0][w];
      c1 += red[1][w];
      c2 += red[2][w];
      s += red[3][w];
      s0 += red[4][w];
      s1 += red[5][w];
      s2 += red[6][w];
    }
    const float v0 = basis[0], v1 = basis[1];
    float lev[4] = {-v0 - v1, -v0 + v1, v0 - v1, v0 + v1};
    float e0[4] = {-1.f, -1.f, 1.f, 1.f};
    float e1[4] = {-1.f, 1.f, -1.f, 1.f};
#define CSWAP(i, j)                                                   \
    if (lev[i] > lev[j]) {                                            \
      float t = lev[i]; lev[i] = lev[j]; lev[j] = t;                  \
      t = e0[i]; e0[i] = e0[j]; e0[j] = t;                            \
      t = e1[i]; e1[i] = e1[j]; e1[j] = t;                            \
    }
    CSWAP(0, 1) CSWAP(2, 3) CSWAP(0, 2) CSWAP(1, 3) CSWAP(1, 2)
#undef CSWAP
    const double A0 = e0[0], A1 = e0[1], A2 = e0[2], A3 = e0[3];
    const double B0 = e1[0], B1 = e1[1], B2 = e1[2], B3 = e1[3];
    const double N = (double)n;
    // telescoped sums over the monotone one-hot
    const double Sb0 = A0 * s + (A1 - A0) * s0 + (A2 - A1) * s1 + (A3 - A2) * s2;
    const double Sb1 = B0 * s + (B1 - B0) * s0 + (B2 - B1) * s1 + (B3 - B2) * s2;
    const double P0 = A0 * B0, P1 = A1 * B1, P2 = A2 * B2, P3 = A3 * B3;
    const double S01 = P0 * N + (P1 - P0) * c0 + (P2 - P1) * c1 + (P3 - P2) * c2;
    const double det = N * N - S01 * S01;
    const double nv0 = (N * Sb0 - S01 * Sb1) / det;
    const double nv1 = (N * Sb1 - S01 * Sb0) / det;
    out_basis[0] = (float)(0.9 * (double)v0 + 0.1 * nv0);
    out_basis[1] = (float)(0.9 * (double)v1 + 0.1 * nv1);
  }
}

extern "C" void kernel_launch(void* const* d_in, const int* in_sizes, int n_in,
                              void* d_out, int out_size, void* d_ws, size_t ws_size,
                              hipStream_t stream) {
  const float* x = (const float*)d_in[0];
  const float* basis = (const float*)d_in[1];
  float* out = (float*)d_out;
  const int n = in_sizes[0];
  float* partials = (float*)d_ws;  // nblocks * 7 floats

  int nblocks = NBLOCKS;
  const int maxb = (int)(ws_size / (7 * sizeof(float)));
  if (nblocks > maxb) nblocks = maxb;
  if (nblocks < 1) nblocks = 1;

  const int n4 = n / 4;
  lq_stats<<<nblocks, NTHREADS, 0, stream>>>(x, basis, partials, n4);
  lq_quant<<<NBLOCKS, NTHREADS, 0, stream>>>(x, basis, out, n, n4);
  lq_final<<<1, NTHREADS, 0, stream>>>(partials, basis, out + n, n, nblocks);
}